// Round 3
// baseline (316.170 us; speedup 1.0000x reference)
//
#include <hip/hip_runtime.h>

// GMLLM dual-stream self-attention, MI355X/gfx950.  Round 6:
//  attn restructured to T3 "minimum 2-phase": double-buffered K/V LDS staging,
//  ONE barrier per tile (stage t+1 issued before compute of t; barrier's auto
//  vmcnt-drain lands after ~2000cy of compute so HBM/L2 latency is hidden).
//   - P pack reverted to truncation (r3-proven; l = ones-MFMA over same bf16 P
//     is exactly consistent regardless of rounding) -> ~4x fewer pack VALU ops.
//   - next-tile mask dword prefetched.
//   - s_setprio(1) around QK and PV MFMA clusters (T5; dbuf creates role-split).
//   - LDS 64KB -> 2 blocks/CU (launch_bounds(256,2)).
//  proj/casts/pack unchanged from round 5 (passing).

typedef __attribute__((ext_vector_type(8))) short short8;   // 8 x bf16 (4 VGPRs) MFMA A/B frag
typedef __attribute__((ext_vector_type(4))) float floatx4;  // MFMA C/D frag

#define LOG2E 1.4426950408889634f
#define QSCL 0.18033688011112042f   /* 0.125 * log2(e) */

static constexpr int Sn = 2048, Dn = 768, Hn = 12, BHn = 48;

__device__ __forceinline__ unsigned short f2bf(float f) {
  unsigned u = __float_as_uint(f);
  u += 0x7FFFu + ((u >> 16) & 1u);          // RNE
  return (unsigned short)(u >> 16);
}

typedef const __attribute__((address_space(1))) unsigned int* gas_t;
typedef __attribute__((address_space(3))) unsigned int* las_t;
__device__ __forceinline__ void async16(const void* g, void* l) {
  // async 16B/lane global->LDS; LDS dest = wave-uniform base + lane*16
  __builtin_amdgcn_global_load_lds((gas_t)g, (las_t)l, 16, 0, 0);
}

// ---------------- cast hidden_states f32 -> bf16 (row-major [8192][768]) ----------------
__global__ void cast_hs_kernel(const float* __restrict__ in, unsigned short* __restrict__ out, int n4) {
  int i = blockIdx.x * 256 + threadIdx.x;
  if (i >= n4) return;
  float4 v = ((const float4*)in)[i];
  ushort4 o = make_ushort4(f2bf(v.x), f2bf(v.y), f2bf(v.z), f2bf(v.w));
  ((ushort4*)out)[i] = o;
}

// ---------------- cast Wq/Wk/Wv f32 -> bf16, stacked [3][768][768] ----------------
__global__ void cast_w_kernel(const float* __restrict__ w0, const float* __restrict__ w1,
                              const float* __restrict__ w2, unsigned short* __restrict__ out) {
  int i = blockIdx.x * 256 + threadIdx.x;
  const float* src = (blockIdx.y == 0) ? w0 : (blockIdx.y == 1) ? w1 : w2;
  float4 v = ((const float4*)src)[i];
  ushort4 o = make_ushort4(f2bf(v.x), f2bf(v.y), f2bf(v.z), f2bf(v.w));
  ((ushort4*)(out + (size_t)blockIdx.y * Dn * Dn))[i] = o;
}

// ---------------- pack layout_q (pre-scaled) / layout_k into upper half of Qc/Kc ----------------
// 8 shorts (16B) per thread: fully coalesced 16B stores.
__global__ void pack_layout_kernel(const float* __restrict__ lq, const float* __restrict__ lk,
                                   unsigned short* __restrict__ Qc, unsigned short* __restrict__ Kc) {
  int idx = blockIdx.x * 256 + threadIdx.x;           // 786432 threads
  const float* src = blockIdx.y ? lk : lq;
  unsigned short* dst = blockIdx.y ? Kc : Qc;
  const float sc = blockIdx.y ? 1.0f : QSCL;
  int d8 = idx & 7;
  int tt = idx >> 3;
  int h = tt % Hn;
  int bs = tt / Hn;
  int b = bs >> 11, s = bs & (Sn - 1);
  float4 v0 = ((const float4*)src)[idx * 2];
  float4 v1 = ((const float4*)src)[idx * 2 + 1];
  short8 o;
  o[0] = (short)f2bf(v0.x * sc); o[1] = (short)f2bf(v0.y * sc);
  o[2] = (short)f2bf(v0.z * sc); o[3] = (short)f2bf(v0.w * sc);
  o[4] = (short)f2bf(v1.x * sc); o[5] = (short)f2bf(v1.y * sc);
  o[6] = (short)f2bf(v1.z * sc); o[7] = (short)f2bf(v1.w * sc);
  size_t off = ((size_t)(b * Hn + h) * Sn + s) * 128 + 64 + d8 * 8;
  *(short8*)(dst + off) = o;
}

// ---------------- QKV projection: C[m,n] = sum_k X[m,k] W[n,k] + bias[n] ----------------
// BK=64 global_load_lds staging (XOR-swizzled), LDS-transposed coalesced epilogue.
// z=0 -> Qc[b,h,s,0:64] (pre-scaled by QSCL), z=1 -> Kc, z=2 -> Vt[b,h,d,s] (transposed)
__global__ __launch_bounds__(256, 3)
void proj_kernel(const unsigned short* __restrict__ X,   // [8192][768] bf16
                 const unsigned short* __restrict__ Wb,  // [3][768][768] bf16
                 const float* __restrict__ bq, const float* __restrict__ bk, const float* __restrict__ bv,
                 unsigned short* __restrict__ Qc, unsigned short* __restrict__ Kc,
                 unsigned short* __restrict__ Vt) {
  __shared__ __align__(16) unsigned short sMem[16384];   // 32KB: K-loop A|B, then epilogue tile
  unsigned short* const sA = sMem;                       // [128][64]
  unsigned short* const sB = sMem + 8192;                // [128][64]

  const int z = blockIdx.z;
  const unsigned short* W = Wb + (size_t)z * Dn * Dn;
  const float* bias = (z == 0) ? bq : (z == 1) ? bk : bv;

  const int t = threadIdx.x;
  const int lane = t & 63, wave = t >> 6;
  const int wm = wave >> 1, wn = wave & 1;
  const int quad = lane >> 4, col15 = lane & 15;
  const int m0 = blockIdx.y * 128, n0 = blockIdx.x * 128;

  const int srow = lane >> 3, schunk = lane & 7;   // staging: 8 rows/call, 8 chunks/row

  floatx4 acc[4][4];
#pragma unroll
  for (int i = 0; i < 4; i++)
#pragma unroll
    for (int j = 0; j < 4; j++) acc[i][j] = (floatx4){0.f, 0.f, 0.f, 0.f};

  for (int k0 = 0; k0 < Dn; k0 += 64) {
    __syncthreads();
#pragma unroll
    for (int c = 0; c < 4; c++) {
      int row = wave * 32 + c * 8 + srow;
      int g = schunk ^ (row & 7);
      async16(X + (size_t)(m0 + row) * Dn + k0 + g * 8, sA + (wave * 32 + c * 8) * 64);
      async16(W + (size_t)(n0 + row) * Dn + k0 + g * 8, sB + (wave * 32 + c * 8) * 64);
    }
    __syncthreads();
#pragma unroll
    for (int kk = 0; kk < 2; kk++) {
      short8 af[4], bf[4];
      const int slot = ((kk * 4 + quad) ^ (col15 & 7)) * 8;
#pragma unroll
      for (int i = 0; i < 4; i++)
        af[i] = *(const short8*)(sA + (wm * 64 + i * 16 + col15) * 64 + slot);
#pragma unroll
      for (int j = 0; j < 4; j++)
        bf[j] = *(const short8*)(sB + (wn * 64 + j * 16 + col15) * 64 + slot);
#pragma unroll
      for (int i = 0; i < 4; i++)
#pragma unroll
        for (int j = 0; j < 4; j++)
          acc[i][j] = __builtin_amdgcn_mfma_f32_16x16x32_bf16(af[i], bf[j], acc[i][j], 0, 0, 0);
    }
  }

  __syncthreads();                                  // K-loop LDS reads done; reuse sMem as tile
  const int b = m0 >> 11;                           // blocks never cross batch boundary
  const int s0g = m0 & (Sn - 1);
  const int h0 = n0 >> 6;

  if (z < 2) {
    // ---- Q/K: LDS tile [m][128n], n XOR-swizzled by (m>>2)&3 on bits 4-5 ----
    const float scl = (z == 0) ? QSCL : 1.0f;
    unsigned short* dst0 = (z == 0) ? Qc : Kc;
#pragma unroll
    for (int j = 0; j < 4; j++) {
      int nl = wn * 64 + j * 16 + col15;
      float bias_n = bias[n0 + nl];
#pragma unroll
      for (int i = 0; i < 4; i++) {
        int mb = wm * 64 + i * 16 + quad * 4;
#pragma unroll
        for (int r = 0; r < 4; r++) {
          int m = mb + r;
          sMem[m * 128 + (nl ^ (((m >> 2) & 3) << 4))] = f2bf((acc[i][j][r] + bias_n) * scl);
        }
      }
    }
    __syncthreads();
#pragma unroll
    for (int cc = 0; cc < 8; cc++) {                // 2048 16B chunks, fully coalesced out
      int idx = cc * 256 + t;
      int m = idx >> 4, piece = idx & 15;
      int h = h0 + (piece >> 3), d8 = piece & 7;
      short8 v = *(const short8*)(sMem + m * 128 + (piece ^ (((m >> 2) & 3) << 1)) * 8);
      *(short8*)(dst0 + ((size_t)(b * Hn + h) * Sn + s0g + m) * 128 + d8 * 8) = v;
    }
  } else {
    // ---- V: LDS tile [n][128m], m XOR-swizzled by n&7 on bits 4-6; packed b64 writes ----
#pragma unroll
    for (int j = 0; j < 4; j++) {
      int nl = wn * 64 + j * 16 + col15;
      float bias_n = bias[n0 + nl];
#pragma unroll
      for (int i = 0; i < 4; i++) {
        int mb = wm * 64 + i * 16 + quad * 4;
        ushort4 pk = make_ushort4(f2bf(acc[i][j][0] + bias_n), f2bf(acc[i][j][1] + bias_n),
                                  f2bf(acc[i][j][2] + bias_n), f2bf(acc[i][j][3] + bias_n));
        *(ushort4*)(sMem + nl * 128 + (mb ^ ((nl & 7) << 4))) = pk;
      }
    }
    __syncthreads();
#pragma unroll
    for (int cc = 0; cc < 8; cc++) {                // coalesced Vt rows (256B per 16 lanes)
      int idx = cc * 256 + t;
      int nl = idx >> 4, piece = idx & 15;
      int h = h0 + (nl >> 6), d = nl & 63;
      short8 v = *(const short8*)(sMem + nl * 128 + (piece ^ ((nl & 7) << 1)) * 8);
      *(short8*)(Vt + ((size_t)(b * Hn + h) * 64 + d) * Sn + s0g + piece * 8) = v;
    }
  }
}

// ---------------- flash attention, swapped operands + 2-phase dbuf: 128 q-rows/block ----------------
// S^T = mfma(K,Q): lane (quad,col15) reg r holds S[q = blk+col15][k = jm*16+quad*4+r].
// P rows lane-local in k -> truncate-pack + b64 LDS writes (physical = k ^ ((q&7)<<3)),
// PV reads b128 B-frags with the same involution.  O^T = mfma(V^T, P^T).
// lsum via ones-row MFMA (exactly consistent with PV: sums the same bf16 P).
// K/V double-buffered: stage(t+1) issued BEFORE compute(t); ONE barrier per tile.
__global__ __launch_bounds__(256, 2)
void attn_kernel(const unsigned short* __restrict__ Qc,  // [BH][S][128], pre-scaled by QSCL
                 const unsigned short* __restrict__ Kc,  // [BH][S][128]
                 const unsigned short* __restrict__ Vt,  // [BH][64][S]
                 const float* __restrict__ mask,         // [B][S]
                 float* __restrict__ out) {              // [B][S][768]
  __shared__ __align__(16) unsigned short sK2[2][64 * 128]; // 32KB, swizzled, pad-free
  __shared__ __align__(16) unsigned short sV2[2][64 * 64];  // 16KB, swizzled, pad-free
  __shared__ __align__(16) unsigned short sS[128 * 64];     // 16KB P^T, wave-private rows

  const int t = threadIdx.x;
  const int lane = t & 63, wave = t >> 6;
  const int quad = lane >> 4, col15 = lane & 15;
  const int swz = (col15 & 7) << 3;                      // sS k swizzle (shorts): phys = k ^ swz

  // XCD-aware swizzle: all 16 q-blocks of one bh share id&7 (L2 K/V reuse)
  const int id = blockIdx.x;
  const int slot = id >> 3;
  const int bh = (id & 7) + 8 * (slot >> 4);
  const int q0 = (slot & 15) * 128;
  const int b = bh / Hn, h = bh % Hn;

  // Q fragments (B-operand: col=q=lane&15, k-rows quad*8)
  short8 aq[2][4];
  const unsigned short* Qbase = Qc + ((size_t)bh * Sn + q0) * 128;
#pragma unroll
  for (int i = 0; i < 2; i++)
#pragma unroll
    for (int kk = 0; kk < 4; kk++)
      aq[i][kk] = *(const short8*)(Qbase + (size_t)(wave * 32 + i * 16 + col15) * 128 + kk * 32 + quad * 8);

  floatx4 O[2][4], lacc[2];
#pragma unroll
  for (int i = 0; i < 2; i++) {
    lacc[i] = (floatx4){0.f, 0.f, 0.f, 0.f};
#pragma unroll
    for (int j = 0; j < 4; j++) O[i][j] = (floatx4){0.f, 0.f, 0.f, 0.f};
  }

  // ones A-frag: row 0 (lanes with col15==0) = 1.0bf16, everything else 0.
  short8 aone;
  {
    short onev = (col15 == 0) ? (short)0x3F80 : (short)0;
#pragma unroll
    for (int e = 0; e < 8; e++) aone[e] = onev;
  }

  const unsigned short* Kbase = Kc + (size_t)bh * Sn * 128;
  const unsigned short* Vbase = Vt + (size_t)bh * 64 * Sn;
  const float* mbase = mask + (size_t)b * Sn;

  const int krow = lane >> 4, kslot = lane & 15;  // sKc staging: 4 rows/call
  const int vrow = lane >> 3, vslot = lane & 7;   // sVt staging: 8 rows/call

  auto stageKV = [&](int tile, int buf) {
    unsigned short* sKn = &sK2[buf][0];
    unsigned short* sVn = &sV2[buf][0];
#pragma unroll
    for (int c = 0; c < 4; c++) {                 // K tile 64x256B, swizzled
      int row = wave * 16 + c * 4 + krow;
      int g = (kslot & 8) | ((kslot ^ row) & 7);
      async16(Kbase + (size_t)(tile * 64 + row) * 128 + g * 8, sKn + (wave * 16 + c * 4) * 128);
    }
#pragma unroll
    for (int c = 0; c < 2; c++) {                 // V^T tile 64x128B, swizzled
      int row = wave * 16 + c * 8 + vrow;
      int g = vslot ^ (row & 7);
      async16(Vbase + (size_t)row * Sn + tile * 64 + g * 8, sVn + (wave * 16 + c * 8) * 64);
    }
  };

  constexpr int NT = Sn / 64;                     // 32 tiles
  stageKV(0, 0);
  float mcur = mbase[lane] * LOG2E;               // tile-0 mask dword
  __syncthreads();                                // drains stage-0 (auto vmcnt(0))

  for (int kt = 0; kt < NT; kt++) {
    const int cur = kt & 1;
    if (kt + 1 < NT) stageKV(kt + 1, cur ^ 1);    // hidden under this tile's compute
    const int tn = (kt + 1 < NT) ? kt + 1 : NT - 1;
    float mnew = mbase[tn * 64 + lane] * LOG2E;   // prefetch next tile's mask
    const bool nomask = __all(mcur == 0.0f);
    const unsigned short* sKcur = &sK2[cur][0];
    const unsigned short* sVcur = &sV2[cur][0];

    // ---- S^T(log2-domain) = Kcat Qcat^T ----
    floatx4 sacc[4][2];                           // [jm = k subtile][iq]
#pragma unroll
    for (int jm = 0; jm < 4; jm++) {
      sacc[jm][0] = (floatx4){0.f, 0.f, 0.f, 0.f};
      sacc[jm][1] = (floatx4){0.f, 0.f, 0.f, 0.f};
    }
    __builtin_amdgcn_s_setprio(1);
#pragma unroll
    for (int kk = 0; kk < 4; kk++) {
      const int slotK = (((kk * 4 + quad) & 8) | (((kk * 4 + quad) ^ col15) & 7)) * 8;
#pragma unroll
      for (int jm = 0; jm < 4; jm++) {
        short8 ak = *(const short8*)(sKcur + (jm * 16 + col15) * 128 + slotK);
        sacc[jm][0] = __builtin_amdgcn_mfma_f32_16x16x32_bf16(ak, aq[0][kk], sacc[jm][0], 0, 0, 0);
        sacc[jm][1] = __builtin_amdgcn_mfma_f32_16x16x32_bf16(ak, aq[1][kk], sacc[jm][1], 0, 0, 0);
      }
    }
    __builtin_amdgcn_s_setprio(0);

    // mask slow path: per-element additive value via lane shuffle (exact)
    float mvv[4][4];
    if (!nomask) {
#pragma unroll
      for (int jm = 0; jm < 4; jm++)
#pragma unroll
        for (int r = 0; r < 4; r++) mvv[jm][r] = __shfl(mcur, jm * 16 + quad * 4 + r);
    }

    // ---- softmax: p = exp2(s (+ mask)); TRUNCATE-pack -> b64 stores into sS[q][k^swz] ----
    // (truncation is exact-consistent: l sums the same truncated bf16 P via MFMA)
#pragma unroll
    for (int iq = 0; iq < 2; iq++) {
      unsigned short* srow = sS + (wave * 32 + iq * 16 + col15) * 64;
#pragma unroll
      for (int jm = 0; jm < 4; jm++) {
        float p0 = sacc[jm][iq][0], p1 = sacc[jm][iq][1];
        float p2 = sacc[jm][iq][2], p3 = sacc[jm][iq][3];
        if (!nomask) { p0 += mvv[jm][0]; p1 += mvv[jm][1]; p2 += mvv[jm][2]; p3 += mvv[jm][3]; }
        p0 = __builtin_amdgcn_exp2f(p0); p1 = __builtin_amdgcn_exp2f(p1);
        p2 = __builtin_amdgcn_exp2f(p2); p3 = __builtin_amdgcn_exp2f(p3);
        uint2 w;
        w.x = (__float_as_uint(p0) >> 16) | (__float_as_uint(p1) & 0xFFFF0000u);
        w.y = (__float_as_uint(p2) >> 16) | (__float_as_uint(p3) & 0xFFFF0000u);
        *(uint2*)(srow + ((jm * 16 + quad * 4) ^ swz)) = w;
      }
    }
    // no barrier: sS rows are wave-private; intra-wave LDS RAW is ordered

    // ---- O^T += V^T P^T ;  l += ones·P^T ----
    __builtin_amdgcn_s_setprio(1);
#pragma unroll
    for (int kk = 0; kk < 2; kk++) {
      short8 pb0 = *(const short8*)(sS + (wave * 32 + col15) * 64 + ((kk * 32 + quad * 8) ^ swz));
      short8 pb1 = *(const short8*)(sS + (wave * 32 + 16 + col15) * 64 + ((kk * 32 + quad * 8) ^ swz));
      const int slotV = ((kk * 4 + quad) ^ (col15 & 7)) * 8;
#pragma unroll
      for (int jd = 0; jd < 4; jd++) {
        short8 av = *(const short8*)(sVcur + (jd * 16 + col15) * 64 + slotV);
        O[0][jd] = __builtin_amdgcn_mfma_f32_16x16x32_bf16(av, pb0, O[0][jd], 0, 0, 0);
        O[1][jd] = __builtin_amdgcn_mfma_f32_16x16x32_bf16(av, pb1, O[1][jd], 0, 0, 0);
      }
      lacc[0] = __builtin_amdgcn_mfma_f32_16x16x32_bf16(aone, pb0, lacc[0], 0, 0, 0);
      lacc[1] = __builtin_amdgcn_mfma_f32_16x16x32_bf16(aone, pb1, lacc[1], 0, 0, 0);
    }
    __builtin_amdgcn_s_setprio(0);

    __syncthreads();  // single barrier: drains stage(t+1) writes + all waves' LDS reads of buf[cur]
    mcur = mnew;
  }

  // ---- epilogue: l for q lives in lane (quad0, q).reg0; broadcast with one shuffle ----
#pragma unroll
  for (int iq = 0; iq < 2; iq++) {
    float inv = 1.0f / __shfl(lacc[iq][0], col15);
    int qrow = q0 + wave * 32 + iq * 16 + col15;
    float* obase = out + ((size_t)b * Sn + qrow) * Dn + h * 64 + quad * 4;
#pragma unroll
    for (int jd = 0; jd < 4; jd++) {
      float4 o4 = make_float4(O[iq][jd][0] * inv, O[iq][jd][1] * inv,
                              O[iq][jd][2] * inv, O[iq][jd][3] * inv);
      *(float4*)(obase + jd * 16) = o4;
    }
  }
}

extern "C" void kernel_launch(void* const* d_in, const int* in_sizes, int n_in,
                              void* d_out, int out_size, void* d_ws, size_t ws_size,
                              hipStream_t stream) {
  const float* hs   = (const float*)d_in[0];
  const float* lq   = (const float*)d_in[1];
  const float* lk   = (const float*)d_in[2];
  const float* mask = (const float*)d_in[3];
  const float* Wq   = (const float*)d_in[4];
  const float* bq   = (const float*)d_in[5];
  const float* Wk   = (const float*)d_in[6];
  const float* bk   = (const float*)d_in[7];
  const float* Wv   = (const float*)d_in[8];
  const float* bv   = (const float*)d_in[9];
  float* out = (float*)d_out;

  char* ws = (char*)d_ws;
  unsigned short* Xbf = (unsigned short*)ws;                         // [8192][768]
  unsigned short* Wbf = (unsigned short*)(ws + 12582912);            // [3][768][768]
  unsigned short* Qc  = (unsigned short*)(ws + 12582912 + 3538944);  // [48][2048][128]
  unsigned short* Kc  = Qc + (size_t)BHn * Sn * 128;
  unsigned short* Vt  = Kc + (size_t)BHn * Sn * 128;                 // [48][64][2048]

  cast_hs_kernel<<<6144, 256, 0, stream>>>(hs, Xbf, 1572864);
  cast_w_kernel<<<dim3(576, 3), 256, 0, stream>>>(Wq, Wk, Wv, Wbf);
  pack_layout_kernel<<<dim3(3072, 2), 256, 0, stream>>>(lq, lk, Qc, Kc);
  proj_kernel<<<dim3(6, 64, 3), 256, 0, stream>>>(Xbf, Wbf, bq, bk, bv, Qc, Kc, Vt);
  attn_kernel<<<768, 256, 0, stream>>>(Qc, Kc, Vt, mask, out);
}

// Round 5
// 285.752 us; speedup vs baseline: 1.1064x; 1.1064x over previous
//
#include <hip/hip_runtime.h>

// GMLLM dual-stream self-attention, MI355X/gfx950.  Round 8 (= round 7 resubmit;
// round-7 bench died on container acquisition, no kernel signal).
//  attn: KT=32 kv-tiles -> LDS 32KB (K dbuf 16 + V dbuf 8 + sS 8) -> 3 blocks/CU
//  co-resident (768 = 256x3, zero tail), single barrier per tile, dbuf staging
//  issued a tile ahead (drain overlapped with compute). Same per-64kv op totals
//  as round 6; only barrier count doubles, amortized by 12 waves/CU.
//   - swapped-operand flash attn: S^T = mfma(K,Q), O^T = mfma(V^T,P^T)
//   - P truncate-pack -> b64 sS writes (phys col = k ^ ((c&3)<<3)), b128 reads
//   - lsum via ones-row MFMA; all-zero-mask fast path; float4 stores
//  proj/casts/pack identical to round 6 (passing).

typedef __attribute__((ext_vector_type(8))) short short8;   // 8 x bf16 (4 VGPRs) MFMA A/B frag
typedef __attribute__((ext_vector_type(4))) float floatx4;  // MFMA C/D frag

#define LOG2E 1.4426950408889634f
#define QSCL 0.18033688011112042f   /* 0.125 * log2(e) */

static constexpr int Sn = 2048, Dn = 768, Hn = 12, BHn = 48;

__device__ __forceinline__ unsigned short f2bf(float f) {
  unsigned u = __float_as_uint(f);
  u += 0x7FFFu + ((u >> 16) & 1u);          // RNE
  return (unsigned short)(u >> 16);
}

typedef const __attribute__((address_space(1))) unsigned int* gas_t;
typedef __attribute__((address_space(3))) unsigned int* las_t;
__device__ __forceinline__ void async16(const void* g, void* l) {
  // async 16B/lane global->LDS; LDS dest = wave-uniform base + lane*16
  __builtin_amdgcn_global_load_lds((gas_t)g, (las_t)l, 16, 0, 0);
}

// ---------------- cast hidden_states f32 -> bf16 (row-major [8192][768]) ----------------
__global__ void cast_hs_kernel(const float* __restrict__ in, unsigned short* __restrict__ out, int n4) {
  int i = blockIdx.x * 256 + threadIdx.x;
  if (i >= n4) return;
  float4 v = ((const float4*)in)[i];
  ushort4 o = make_ushort4(f2bf(v.x), f2bf(v.y), f2bf(v.z), f2bf(v.w));
  ((ushort4*)out)[i] = o;
}

// ---------------- cast Wq/Wk/Wv f32 -> bf16, stacked [3][768][768] ----------------
__global__ void cast_w_kernel(const float* __restrict__ w0, const float* __restrict__ w1,
                              const float* __restrict__ w2, unsigned short* __restrict__ out) {
  int i = blockIdx.x * 256 + threadIdx.x;
  const float* src = (blockIdx.y == 0) ? w0 : (blockIdx.y == 1) ? w1 : w2;
  float4 v = ((const float4*)src)[i];
  ushort4 o = make_ushort4(f2bf(v.x), f2bf(v.y), f2bf(v.z), f2bf(v.w));
  ((ushort4*)(out + (size_t)blockIdx.y * Dn * Dn))[i] = o;
}

// ---------------- pack layout_q (pre-scaled) / layout_k into upper half of Qc/Kc ----------------
// 8 shorts (16B) per thread: fully coalesced 16B stores.
__global__ void pack_layout_kernel(const float* __restrict__ lq, const float* __restrict__ lk,
                                   unsigned short* __restrict__ Qc, unsigned short* __restrict__ Kc) {
  int idx = blockIdx.x * 256 + threadIdx.x;           // 786432 threads
  const float* src = blockIdx.y ? lk : lq;
  unsigned short* dst = blockIdx.y ? Kc : Qc;
  const float sc = blockIdx.y ? 1.0f : QSCL;
  int d8 = idx & 7;
  int tt = idx >> 3;
  int h = tt % Hn;
  int bs = tt / Hn;
  int b = bs >> 11, s = bs & (Sn - 1);
  float4 v0 = ((const float4*)src)[idx * 2];
  float4 v1 = ((const float4*)src)[idx * 2 + 1];
  short8 o;
  o[0] = (short)f2bf(v0.x * sc); o[1] = (short)f2bf(v0.y * sc);
  o[2] = (short)f2bf(v0.z * sc); o[3] = (short)f2bf(v0.w * sc);
  o[4] = (short)f2bf(v1.x * sc); o[5] = (short)f2bf(v1.y * sc);
  o[6] = (short)f2bf(v1.z * sc); o[7] = (short)f2bf(v1.w * sc);
  size_t off = ((size_t)(b * Hn + h) * Sn + s) * 128 + 64 + d8 * 8;
  *(short8*)(dst + off) = o;
}

// ---------------- QKV projection: C[m,n] = sum_k X[m,k] W[n,k] + bias[n] ----------------
// BK=64 global_load_lds staging (XOR-swizzled), LDS-transposed coalesced epilogue.
// z=0 -> Qc[b,h,s,0:64] (pre-scaled by QSCL), z=1 -> Kc, z=2 -> Vt[b,h,d,s] (transposed)
__global__ __launch_bounds__(256, 3)
void proj_kernel(const unsigned short* __restrict__ X,   // [8192][768] bf16
                 const unsigned short* __restrict__ Wb,  // [3][768][768] bf16
                 const float* __restrict__ bq, const float* __restrict__ bk, const float* __restrict__ bv,
                 unsigned short* __restrict__ Qc, unsigned short* __restrict__ Kc,
                 unsigned short* __restrict__ Vt) {
  __shared__ __align__(16) unsigned short sMem[16384];   // 32KB: K-loop A|B, then epilogue tile
  unsigned short* const sA = sMem;                       // [128][64]
  unsigned short* const sB = sMem + 8192;                // [128][64]

  const int z = blockIdx.z;
  const unsigned short* W = Wb + (size_t)z * Dn * Dn;
  const float* bias = (z == 0) ? bq : (z == 1) ? bk : bv;

  const int t = threadIdx.x;
  const int lane = t & 63, wave = t >> 6;
  const int wm = wave >> 1, wn = wave & 1;
  const int quad = lane >> 4, col15 = lane & 15;
  const int m0 = blockIdx.y * 128, n0 = blockIdx.x * 128;

  const int srow = lane >> 3, schunk = lane & 7;   // staging: 8 rows/call, 8 chunks/row

  floatx4 acc[4][4];
#pragma unroll
  for (int i = 0; i < 4; i++)
#pragma unroll
    for (int j = 0; j < 4; j++) acc[i][j] = (floatx4){0.f, 0.f, 0.f, 0.f};

  for (int k0 = 0; k0 < Dn; k0 += 64) {
    __syncthreads();
#pragma unroll
    for (int c = 0; c < 4; c++) {
      int row = wave * 32 + c * 8 + srow;
      int g = schunk ^ (row & 7);
      async16(X + (size_t)(m0 + row) * Dn + k0 + g * 8, sA + (wave * 32 + c * 8) * 64);
      async16(W + (size_t)(n0 + row) * Dn + k0 + g * 8, sB + (wave * 32 + c * 8) * 64);
    }
    __syncthreads();
#pragma unroll
    for (int kk = 0; kk < 2; kk++) {
      short8 af[4], bf[4];
      const int slot = ((kk * 4 + quad) ^ (col15 & 7)) * 8;
#pragma unroll
      for (int i = 0; i < 4; i++)
        af[i] = *(const short8*)(sA + (wm * 64 + i * 16 + col15) * 64 + slot);
#pragma unroll
      for (int j = 0; j < 4; j++)
        bf[j] = *(const short8*)(sB + (wn * 64 + j * 16 + col15) * 64 + slot);
#pragma unroll
      for (int i = 0; i < 4; i++)
#pragma unroll
        for (int j = 0; j < 4; j++)
          acc[i][j] = __builtin_amdgcn_mfma_f32_16x16x32_bf16(af[i], bf[j], acc[i][j], 0, 0, 0);
    }
  }

  __syncthreads();                                  // K-loop LDS reads done; reuse sMem as tile
  const int b = m0 >> 11;                           // blocks never cross batch boundary
  const int s0g = m0 & (Sn - 1);
  const int h0 = n0 >> 6;

  if (z < 2) {
    // ---- Q/K: LDS tile [m][128n], n XOR-swizzled by (m>>2)&3 on bits 4-5 ----
    const float scl = (z == 0) ? QSCL : 1.0f;
    unsigned short* dst0 = (z == 0) ? Qc : Kc;
#pragma unroll
    for (int j = 0; j < 4; j++) {
      int nl = wn * 64 + j * 16 + col15;
      float bias_n = bias[n0 + nl];
#pragma unroll
      for (int i = 0; i < 4; i++) {
        int mb = wm * 64 + i * 16 + quad * 4;
#pragma unroll
        for (int r = 0; r < 4; r++) {
          int m = mb + r;
          sMem[m * 128 + (nl ^ (((m >> 2) & 3) << 4))] = f2bf((acc[i][j][r] + bias_n) * scl);
        }
      }
    }
    __syncthreads();
#pragma unroll
    for (int cc = 0; cc < 8; cc++) {                // 2048 16B chunks, fully coalesced out
      int idx = cc * 256 + t;
      int m = idx >> 4, piece = idx & 15;
      int h = h0 + (piece >> 3), d8 = piece & 7;
      short8 v = *(const short8*)(sMem + m * 128 + (piece ^ (((m >> 2) & 3) << 1)) * 8);
      *(short8*)(dst0 + ((size_t)(b * Hn + h) * Sn + s0g + m) * 128 + d8 * 8) = v;
    }
  } else {
    // ---- V: LDS tile [n][128m], m XOR-swizzled by n&7 on bits 4-6; packed b64 writes ----
#pragma unroll
    for (int j = 0; j < 4; j++) {
      int nl = wn * 64 + j * 16 + col15;
      float bias_n = bias[n0 + nl];
#pragma unroll
      for (int i = 0; i < 4; i++) {
        int mb = wm * 64 + i * 16 + quad * 4;
        ushort4 pk = make_ushort4(f2bf(acc[i][j][0] + bias_n), f2bf(acc[i][j][1] + bias_n),
                                  f2bf(acc[i][j][2] + bias_n), f2bf(acc[i][j][3] + bias_n));
        *(ushort4*)(sMem + nl * 128 + (mb ^ ((nl & 7) << 4))) = pk;
      }
    }
    __syncthreads();
#pragma unroll
    for (int cc = 0; cc < 8; cc++) {                // coalesced Vt rows (256B per 16 lanes)
      int idx = cc * 256 + t;
      int nl = idx >> 4, piece = idx & 15;
      int h = h0 + (nl >> 6), d = nl & 63;
      short8 v = *(const short8*)(sMem + nl * 128 + (piece ^ ((nl & 7) << 1)) * 8);
      *(short8*)(Vt + ((size_t)(b * Hn + h) * 64 + d) * Sn + s0g + piece * 8) = v;
    }
  }
}

// ---------------- flash attention: swapped operands, KT=32, dbuf, 1 barrier/tile ----------------
// S^T = mfma(K,Q): lane (quad,col15) reg r holds S[q = blk+col15][k = jm*16+quad*4+r], jm<2.
// P truncate-packed -> b64 sS writes at phys col = k ^ ((col15&3)<<3); PV reads b128 with
// the same involution.  O^T = mfma(V^T, P^T).  lsum via ones-row MFMA.
// LDS 32KB -> 3 blocks/CU (grid 768 = 256x3, zero tail).
__global__ __launch_bounds__(256, 3)
void attn_kernel(const unsigned short* __restrict__ Qc,  // [BH][S][128], pre-scaled by QSCL
                 const unsigned short* __restrict__ Kc,  // [BH][S][128]
                 const unsigned short* __restrict__ Vt,  // [BH][64][S]
                 const float* __restrict__ mask,         // [B][S]
                 float* __restrict__ out) {              // [B][S][768]
  __shared__ __align__(16) unsigned short sK2[2][32 * 128]; // 16KB, swizzled, pad-free
  __shared__ __align__(16) unsigned short sV2[2][64 * 32];  // 8KB, swizzled, pad-free
  __shared__ __align__(16) unsigned short sS[128 * 32];     // 8KB P^T, wave-private rows

  const int t = threadIdx.x;
  const int lane = t & 63, wave = t >> 6;
  const int quad = lane >> 4, col15 = lane & 15;
  const int swz = (col15 & 3) << 3;                      // sS k swizzle (shorts): phys = k ^ swz

  // XCD-aware swizzle: all 16 q-blocks of one bh share id&7 (L2 K/V reuse)
  const int id = blockIdx.x;
  const int slot = id >> 3;
  const int bh = (id & 7) + 8 * (slot >> 4);
  const int q0 = (slot & 15) * 128;
  const int b = bh / Hn, h = bh % Hn;

  // Q fragments (B-operand: col=q=lane&15, k-rows quad*8)
  short8 aq[2][4];
  const unsigned short* Qbase = Qc + ((size_t)bh * Sn + q0) * 128;
#pragma unroll
  for (int i = 0; i < 2; i++)
#pragma unroll
    for (int kk = 0; kk < 4; kk++)
      aq[i][kk] = *(const short8*)(Qbase + (size_t)(wave * 32 + i * 16 + col15) * 128 + kk * 32 + quad * 8);

  floatx4 O[2][4], lacc[2];
#pragma unroll
  for (int i = 0; i < 2; i++) {
    lacc[i] = (floatx4){0.f, 0.f, 0.f, 0.f};
#pragma unroll
    for (int j = 0; j < 4; j++) O[i][j] = (floatx4){0.f, 0.f, 0.f, 0.f};
  }

  // ones A-frag: row 0 (lanes with col15==0) = 1.0bf16, everything else 0.
  short8 aone;
  {
    short onev = (col15 == 0) ? (short)0x3F80 : (short)0;
#pragma unroll
    for (int e = 0; e < 8; e++) aone[e] = onev;
  }

  const unsigned short* Kbase = Kc + (size_t)bh * Sn * 128;
  const unsigned short* Vbase = Vt + (size_t)bh * 64 * Sn;
  const float* mbase = mask + (size_t)b * Sn;

  const int krow = lane >> 4, kslot = lane & 15;  // sK staging: 4 rows/call, 16 chunks
  const int vrow = lane >> 2, vchunk = lane & 3;  // sV staging: 16 rows/call, 4 chunks

  auto stageKV = [&](int tile, int buf) {
    unsigned short* sKn = &sK2[buf][0];
    unsigned short* sVn = &sV2[buf][0];
#pragma unroll
    for (int c = 0; c < 2; c++) {                 // K tile 32x256B, swizzled chunks of 16B
      int row = wave * 8 + c * 4 + krow;
      int g = (kslot & 8) | ((kslot ^ row) & 7);
      async16(Kbase + (size_t)(tile * 32 + row) * 128 + g * 8, sKn + (wave * 8 + c * 4) * 128);
    }
    {                                             // V^T tile 64x64B, swizzled chunks of 16B
      int row = wave * 16 + vrow;
      int g = vchunk ^ (row & 3);
      async16(Vbase + (size_t)row * Sn + tile * 32 + g * 8, sVn + (wave * 16) * 32);
    }
  };

  constexpr int NT = Sn / 32;                     // 64 tiles
  stageKV(0, 0);
  float mcur = mbase[lane & 31] * LOG2E;          // tile-0 mask (32 values, lanes duplicated)
  __syncthreads();                                // drains stage-0 (auto vmcnt(0))

  for (int kt = 0; kt < NT; kt++) {
    const int cur = kt & 1;
    if (kt + 1 < NT) stageKV(kt + 1, cur ^ 1);    // hidden under this tile's compute
    const int tn = (kt + 1 < NT) ? kt + 1 : NT - 1;
    float mnew = mbase[tn * 32 + (lane & 31)] * LOG2E;
    const bool nomask = __all(mcur == 0.0f);
    const unsigned short* sKcur = &sK2[cur][0];
    const unsigned short* sVcur = &sV2[cur][0];

    // ---- S^T(log2-domain) = Kcat Qcat^T ----
    floatx4 sacc[2][2];                           // [jm = k subtile][iq]
#pragma unroll
    for (int jm = 0; jm < 2; jm++) {
      sacc[jm][0] = (floatx4){0.f, 0.f, 0.f, 0.f};
      sacc[jm][1] = (floatx4){0.f, 0.f, 0.f, 0.f};
    }
    __builtin_amdgcn_s_setprio(1);
#pragma unroll
    for (int kk = 0; kk < 4; kk++) {
      const int slotK = (((kk * 4 + quad) & 8) | (((kk * 4 + quad) ^ col15) & 7)) * 8;
#pragma unroll
      for (int jm = 0; jm < 2; jm++) {
        short8 ak = *(const short8*)(sKcur + (jm * 16 + col15) * 128 + slotK);
        sacc[jm][0] = __builtin_amdgcn_mfma_f32_16x16x32_bf16(ak, aq[0][kk], sacc[jm][0], 0, 0, 0);
        sacc[jm][1] = __builtin_amdgcn_mfma_f32_16x16x32_bf16(ak, aq[1][kk], sacc[jm][1], 0, 0, 0);
      }
    }
    __builtin_amdgcn_s_setprio(0);

    // mask slow path: per-element additive value via lane shuffle (exact)
    float mvv[2][4];
    if (!nomask) {
#pragma unroll
      for (int jm = 0; jm < 2; jm++)
#pragma unroll
        for (int r = 0; r < 4; r++) mvv[jm][r] = __shfl(mcur, jm * 16 + quad * 4 + r);
    }

    // ---- softmax: p = exp2(s (+ mask)); TRUNCATE-pack -> b64 stores into sS[q][k^swz] ----
    // (truncation is exact-consistent: l sums the same truncated bf16 P via MFMA)
#pragma unroll
    for (int iq = 0; iq < 2; iq++) {
      unsigned short* srow = sS + (wave * 32 + iq * 16 + col15) * 32;
#pragma unroll
      for (int jm = 0; jm < 2; jm++) {
        float p0 = sacc[jm][iq][0], p1 = sacc[jm][iq][1];
        float p2 = sacc[jm][iq][2], p3 = sacc[jm][iq][3];
        if (!nomask) { p0 += mvv[jm][0]; p1 += mvv[jm][1]; p2 += mvv[jm][2]; p3 += mvv[jm][3]; }
        p0 = __builtin_amdgcn_exp2f(p0); p1 = __builtin_amdgcn_exp2f(p1);
        p2 = __builtin_amdgcn_exp2f(p2); p3 = __builtin_amdgcn_exp2f(p3);
        uint2 w;
        w.x = (__float_as_uint(p0) >> 16) | (__float_as_uint(p1) & 0xFFFF0000u);
        w.y = (__float_as_uint(p2) >> 16) | (__float_as_uint(p3) & 0xFFFF0000u);
        *(uint2*)(srow + ((jm * 16 + quad * 4) ^ swz)) = w;
      }
    }
    // no barrier: sS rows are wave-private; intra-wave LDS RAW is ordered

    // ---- O^T += V^T P^T ;  l += ones·P^T  (single K=32 step) ----
    __builtin_amdgcn_s_setprio(1);
    {
      short8 pb0 = *(const short8*)(sS + (wave * 32 + col15) * 32 + ((quad * 8) ^ swz));
      short8 pb1 = *(const short8*)(sS + (wave * 32 + 16 + col15) * 32 + ((quad * 8) ^ swz));
      const int slotV = (quad ^ (col15 & 3)) * 8;
#pragma unroll
      for (int jd = 0; jd < 4; jd++) {
        short8 av = *(const short8*)(sVcur + (jd * 16 + col15) * 32 + slotV);
        O[0][jd] = __builtin_amdgcn_mfma_f32_16x16x32_bf16(av, pb0, O[0][jd], 0, 0, 0);
        O[1][jd] = __builtin_amdgcn_mfma_f32_16x16x32_bf16(av, pb1, O[1][jd], 0, 0, 0);
      }
      lacc[0] = __builtin_amdgcn_mfma_f32_16x16x32_bf16(aone, pb0, lacc[0], 0, 0, 0);
      lacc[1] = __builtin_amdgcn_mfma_f32_16x16x32_bf16(aone, pb1, lacc[1], 0, 0, 0);
    }
    __builtin_amdgcn_s_setprio(0);

    __syncthreads();  // single barrier: drains stage(t+1) writes + all waves' reads of buf[cur]
    mcur = mnew;
  }

  // ---- epilogue: l for q lives in lane (quad0, q).reg0; broadcast with one shuffle ----
#pragma unroll
  for (int iq = 0; iq < 2; iq++) {
    float inv = 1.0f / __shfl(lacc[iq][0], col15);
    int qrow = q0 + wave * 32 + iq * 16 + col15;
    float* obase = out + ((size_t)b * Sn + qrow) * Dn + h * 64 + quad * 4;
#pragma unroll
    for (int jd = 0; jd < 4; jd++) {
      float4 o4 = make_float4(O[iq][jd][0] * inv, O[iq][jd][1] * inv,
                              O[iq][jd][2] * inv, O[iq][jd][3] * inv);
      *(float4*)(obase + jd * 16) = o4;
    }
  }
}

extern "C" void kernel_launch(void* const* d_in, const int* in_sizes, int n_in,
                              void* d_out, int out_size, void* d_ws, size_t ws_size,
                              hipStream_t stream) {
  const float* hs   = (const float*)d_in[0];
  const float* lq   = (const float*)d_in[1];
  const float* lk   = (const float*)d_in[2];
  const float* mask = (const float*)d_in[3];
  const float* Wq   = (const float*)d_in[4];
  const float* bq   = (const float*)d_in[5];
  const float* Wk   = (const float*)d_in[6];
  const float* bk   = (const float*)d_in[7];
  const float* Wv   = (const float*)d_in[8];
  const float* bv   = (const float*)d_in[9];
  float* out = (float*)d_out;

  char* ws = (char*)d_ws;
  unsigned short* Xbf = (unsigned short*)ws;                         // [8192][768]
  unsigned short* Wbf = (unsigned short*)(ws + 12582912);            // [3][768][768]
  unsigned short* Qc  = (unsigned short*)(ws + 12582912 + 3538944);  // [48][2048][128]
  unsigned short* Kc  = Qc + (size_t)BHn * Sn * 128;
  unsigned short* Vt  = Kc + (size_t)BHn * Sn * 128;                 // [48][64][2048]

  cast_hs_kernel<<<6144, 256, 0, stream>>>(hs, Xbf, 1572864);
  cast_w_kernel<<<dim3(576, 3), 256, 0, stream>>>(Wq, Wk, Wv, Wbf);
  pack_layout_kernel<<<dim3(3072, 2), 256, 0, stream>>>(lq, lk, Qc, Kc);
  proj_kernel<<<dim3(6, 64, 3), 256, 0, stream>>>(Xbf, Wbf, bq, bk, bv, Qc, Kc, Vt);
  attn_kernel<<<768, 256, 0, stream>>>(Qc, Kc, Vt, mask, out);
}

// Round 6
// 276.188 us; speedup vs baseline: 1.1448x; 1.0346x over previous
//
#include <hip/hip_runtime.h>

// GMLLM dual-stream self-attention, MI355X/gfx950.  Round 9:
//  - attn: REVERTED to the round-0 kernel verbatim (best measured: 110.9 us).
//    5 rounds of swapped-operand/dbuf restructuring never beat it (best 117.2).
//  - proj: NEW 2-phase pipeline (the structure that passed in r8 attn):
//    BK=32 double-buffered staging, stage(kt+1) issued BEFORE compute(kt),
//    ONE barrier per K-step (was: issue->barrier(vmcnt0)->compute, full memory
//    latency exposed 12x/block). 24 steps, LDS 32KB (4x8KB dbuf, epilogue reuse),
//    3 blocks/CU. 32-short rows: read pattern (row=col15, chunk=quad) hits the
//    b128 bank floor naturally -> NO swizzle, linear global_load_lds staging.
//  - pack: r5 16B-store version (passing since r5). casts unchanged.

typedef __attribute__((ext_vector_type(8))) short short8;   // 8 x bf16 (4 VGPRs) MFMA A/B frag
typedef __attribute__((ext_vector_type(4))) float floatx4;  // MFMA C/D frag

#define LOG2E 1.4426950408889634f
#define QSCL 0.18033688011112042f   /* 0.125 * log2(e) */

static constexpr int Sn = 2048, Dn = 768, Hn = 12, BHn = 48;

__device__ __forceinline__ unsigned short f2bf(float f) {
  unsigned u = __float_as_uint(f);
  u += 0x7FFFu + ((u >> 16) & 1u);          // RNE
  return (unsigned short)(u >> 16);
}

typedef const __attribute__((address_space(1))) unsigned int* gas_t;
typedef __attribute__((address_space(3))) unsigned int* las_t;
__device__ __forceinline__ void async16(const void* g, void* l) {
  // async 16B/lane global->LDS; LDS dest = wave-uniform base + lane*16
  __builtin_amdgcn_global_load_lds((gas_t)g, (las_t)l, 16, 0, 0);
}

// ---------------- cast hidden_states f32 -> bf16 (row-major [8192][768]) ----------------
__global__ void cast_hs_kernel(const float* __restrict__ in, unsigned short* __restrict__ out, int n4) {
  int i = blockIdx.x * 256 + threadIdx.x;
  if (i >= n4) return;
  float4 v = ((const float4*)in)[i];
  ushort4 o = make_ushort4(f2bf(v.x), f2bf(v.y), f2bf(v.z), f2bf(v.w));
  ((ushort4*)out)[i] = o;
}

// ---------------- cast Wq/Wk/Wv f32 -> bf16, stacked [3][768][768] ----------------
__global__ void cast_w_kernel(const float* __restrict__ w0, const float* __restrict__ w1,
                              const float* __restrict__ w2, unsigned short* __restrict__ out) {
  int i = blockIdx.x * 256 + threadIdx.x;
  const float* src = (blockIdx.y == 0) ? w0 : (blockIdx.y == 1) ? w1 : w2;
  float4 v = ((const float4*)src)[i];
  ushort4 o = make_ushort4(f2bf(v.x), f2bf(v.y), f2bf(v.z), f2bf(v.w));
  ((ushort4*)(out + (size_t)blockIdx.y * Dn * Dn))[i] = o;
}

// ---------------- pack layout_q (pre-scaled) / layout_k into upper half of Qc/Kc ----------------
// 8 shorts (16B) per thread: fully coalesced 16B stores.
__global__ void pack_layout_kernel(const float* __restrict__ lq, const float* __restrict__ lk,
                                   unsigned short* __restrict__ Qc, unsigned short* __restrict__ Kc) {
  int idx = blockIdx.x * 256 + threadIdx.x;           // 786432 threads
  const float* src = blockIdx.y ? lk : lq;
  unsigned short* dst = blockIdx.y ? Kc : Qc;
  const float sc = blockIdx.y ? 1.0f : QSCL;
  int d8 = idx & 7;
  int tt = idx >> 3;
  int h = tt % Hn;
  int bs = tt / Hn;
  int b = bs >> 11, s = bs & (Sn - 1);
  float4 v0 = ((const float4*)src)[idx * 2];
  float4 v1 = ((const float4*)src)[idx * 2 + 1];
  short8 o;
  o[0] = (short)f2bf(v0.x * sc); o[1] = (short)f2bf(v0.y * sc);
  o[2] = (short)f2bf(v0.z * sc); o[3] = (short)f2bf(v0.w * sc);
  o[4] = (short)f2bf(v1.x * sc); o[5] = (short)f2bf(v1.y * sc);
  o[6] = (short)f2bf(v1.z * sc); o[7] = (short)f2bf(v1.w * sc);
  size_t off = ((size_t)(b * Hn + h) * Sn + s) * 128 + 64 + d8 * 8;
  *(short8*)(dst + off) = o;
}

// ---------------- QKV projection: C[m,n] = sum_k X[m,k] W[n,k] + bias[n] ----------------
// BK=32, double-buffered global_load_lds staging (linear, no swizzle needed at 64B rows),
// stage(kt+1) before compute(kt), ONE barrier per K-step. LDS-transposed coalesced epilogue.
// z=0 -> Qc[b,h,s,0:64] (pre-scaled by QSCL), z=1 -> Kc, z=2 -> Vt[b,h,d,s] (transposed)
__global__ __launch_bounds__(256, 3)
void proj_kernel(const unsigned short* __restrict__ X,   // [8192][768] bf16
                 const unsigned short* __restrict__ Wb,  // [3][768][768] bf16
                 const float* __restrict__ bq, const float* __restrict__ bk, const float* __restrict__ bv,
                 unsigned short* __restrict__ Qc, unsigned short* __restrict__ Kc,
                 unsigned short* __restrict__ Vt) {
  // 32KB: K-loop dbuf A0|A1|B0|B1 ([128][32] each), then epilogue tile [128][128]
  __shared__ __align__(16) unsigned short sMem[16384];

  const int z = blockIdx.z;
  const unsigned short* W = Wb + (size_t)z * Dn * Dn;
  const float* bias = (z == 0) ? bq : (z == 1) ? bk : bv;

  const int t = threadIdx.x;
  const int lane = t & 63, wave = t >> 6;
  const int wm = wave >> 1, wn = wave & 1;
  const int quad = lane >> 4, col15 = lane & 15;
  const int m0 = blockIdx.y * 128, n0 = blockIdx.x * 128;

  const int srow = lane >> 2, schunk = lane & 3;   // staging: 16 rows/call, 4 chunks/row

  floatx4 acc[4][4];
#pragma unroll
  for (int i = 0; i < 4; i++)
#pragma unroll
    for (int j = 0; j < 4; j++) acc[i][j] = (floatx4){0.f, 0.f, 0.f, 0.f};

  auto stageAB = [&](int kt, int buf) {
    unsigned short* sA = sMem + buf * 4096;
    unsigned short* sB = sMem + 8192 + buf * 4096;
#pragma unroll
    for (int c = 0; c < 2; c++) {
      int row = wave * 32 + c * 16 + srow;
      async16(X + (size_t)(m0 + row) * Dn + kt * 32 + schunk * 8, sA + (wave * 32 + c * 16) * 32);
      async16(W + (size_t)(n0 + row) * Dn + kt * 32 + schunk * 8, sB + (wave * 32 + c * 16) * 32);
    }
  };

  stageAB(0, 0);
  __syncthreads();                                 // drain stage-0

  for (int kt = 0; kt < 24; kt++) {
    const int cur = kt & 1;
    if (kt + 1 < 24) stageAB(kt + 1, cur ^ 1);     // hidden under this step's compute
    const unsigned short* sA = sMem + cur * 4096;
    const unsigned short* sB = sMem + 8192 + cur * 4096;
    short8 af[4], bf[4];
#pragma unroll
    for (int i = 0; i < 4; i++)
      af[i] = *(const short8*)(sA + (wm * 64 + i * 16 + col15) * 32 + quad * 8);
#pragma unroll
    for (int j = 0; j < 4; j++)
      bf[j] = *(const short8*)(sB + (wn * 64 + j * 16 + col15) * 32 + quad * 8);
#pragma unroll
    for (int i = 0; i < 4; i++)
#pragma unroll
      for (int j = 0; j < 4; j++)
        acc[i][j] = __builtin_amdgcn_mfma_f32_16x16x32_bf16(af[i], bf[j], acc[i][j], 0, 0, 0);
    __syncthreads();                               // next-stage writes done + buf reads done
  }

  const int b = m0 >> 11;                           // blocks never cross batch boundary
  const int s0g = m0 & (Sn - 1);
  const int h0 = n0 >> 6;

  if (z < 2) {
    // ---- Q/K: LDS tile [m][128n], n XOR-swizzled by (m>>2)&3 on bits 4-5 ----
    const float scl = (z == 0) ? QSCL : 1.0f;
    unsigned short* dst0 = (z == 0) ? Qc : Kc;
#pragma unroll
    for (int j = 0; j < 4; j++) {
      int nl = wn * 64 + j * 16 + col15;
      float bias_n = bias[n0 + nl];
#pragma unroll
      for (int i = 0; i < 4; i++) {
        int mb = wm * 64 + i * 16 + quad * 4;
#pragma unroll
        for (int r = 0; r < 4; r++) {
          int m = mb + r;
          sMem[m * 128 + (nl ^ (((m >> 2) & 3) << 4))] = f2bf((acc[i][j][r] + bias_n) * scl);
        }
      }
    }
    __syncthreads();
#pragma unroll
    for (int cc = 0; cc < 8; cc++) {                // 2048 16B chunks, fully coalesced out
      int idx = cc * 256 + t;
      int m = idx >> 4, piece = idx & 15;
      int h = h0 + (piece >> 3), d8 = piece & 7;
      short8 v = *(const short8*)(sMem + m * 128 + (piece ^ (((m >> 2) & 3) << 1)) * 8);
      *(short8*)(dst0 + ((size_t)(b * Hn + h) * Sn + s0g + m) * 128 + d8 * 8) = v;
    }
  } else {
    // ---- V: LDS tile [n][128m], m XOR-swizzled by n&7 on bits 4-6; packed b64 writes ----
#pragma unroll
    for (int j = 0; j < 4; j++) {
      int nl = wn * 64 + j * 16 + col15;
      float bias_n = bias[n0 + nl];
#pragma unroll
      for (int i = 0; i < 4; i++) {
        int mb = wm * 64 + i * 16 + quad * 4;
        ushort4 pk = make_ushort4(f2bf(acc[i][j][0] + bias_n), f2bf(acc[i][j][1] + bias_n),
                                  f2bf(acc[i][j][2] + bias_n), f2bf(acc[i][j][3] + bias_n));
        *(ushort4*)(sMem + nl * 128 + (mb ^ ((nl & 7) << 4))) = pk;
      }
    }
    __syncthreads();
#pragma unroll
    for (int cc = 0; cc < 8; cc++) {                // coalesced Vt rows (256B per 16 lanes)
      int idx = cc * 256 + t;
      int nl = idx >> 4, piece = idx & 15;
      int h = h0 + (nl >> 6), d = nl & 63;
      short8 v = *(const short8*)(sMem + nl * 128 + (piece ^ ((nl & 7) << 1)) * 8);
      *(short8*)(Vt + ((size_t)(b * Hn + h) * 64 + d) * Sn + s0g + piece * 8) = v;
    }
  }
}

// ---------------- flash attention: 128 q-rows/block, KT=64, qk-dim 128, v-dim 64 ----------------
// Round-0 kernel verbatim (best measured: 110.9 us).
// No-max softmax (logits bounded; exact by shift-invariance). lsum per-lane, reduced once.
// P is wave-private in LDS -> only 2 barriers/tile.
__global__ __launch_bounds__(256, 3)
void attn_kernel(const unsigned short* __restrict__ Qc,  // [BH][S][128], pre-scaled by QSCL
                 const unsigned short* __restrict__ Kc,  // [BH][S][128]
                 const unsigned short* __restrict__ Vt,  // [BH][64][S]
                 const float* __restrict__ mask,         // [B][S]
                 float* __restrict__ out) {              // [B][S][768]
  constexpr int LDV = 72;                                // sS stride
  __shared__ __align__(16) unsigned short sKc[64 * 128]; // swizzled, pad-free
  __shared__ __align__(16) unsigned short sVt[64 * 64];  // swizzled, pad-free
  __shared__ __align__(16) unsigned short sS[128 * LDV]; // P (bf16), wave-private rows

  const int t = threadIdx.x;
  const int lane = t & 63, wave = t >> 6;
  const int quad = lane >> 4, col15 = lane & 15;

  // XCD-aware swizzle: all 16 q-blocks of one bh share id&7 (L2 K/V reuse)
  const int id = blockIdx.x;
  const int slot = id >> 3;
  const int bh = (id & 7) + 8 * (slot >> 4);
  const int q0 = (slot & 15) * 128;
  const int b = bh / Hn, h = bh % Hn;

  // Q fragments (concat content+layout, k-dim 128) live in registers all 32 tiles.
  short8 aq[2][4];
  const unsigned short* Qbase = Qc + ((size_t)bh * Sn + q0) * 128;
#pragma unroll
  for (int i = 0; i < 2; i++)
#pragma unroll
    for (int kk = 0; kk < 4; kk++)
      aq[i][kk] = *(const short8*)(Qbase + (size_t)(wave * 32 + i * 16 + col15) * 128 + kk * 32 + quad * 8);

  floatx4 O[2][4];
#pragma unroll
  for (int i = 0; i < 2; i++)
#pragma unroll
    for (int j = 0; j < 4; j++) O[i][j] = (floatx4){0.f, 0.f, 0.f, 0.f};
  float lsum[2][4];
#pragma unroll
  for (int i = 0; i < 2; i++)
#pragma unroll
    for (int r = 0; r < 4; r++) lsum[i][r] = 0.f;

  const unsigned short* Kbase = Kc + (size_t)bh * Sn * 128;
  const unsigned short* Vbase = Vt + (size_t)bh * 64 * Sn;
  const float* mbase = mask + (size_t)b * Sn;

  const int krow = lane >> 4, kslot = lane & 15;  // sKc staging: 4 rows/call
  const int vrow = lane >> 3, vslot = lane & 7;   // sVt staging: 8 rows/call

  for (int kt = 0; kt < Sn / 64; kt++) {
    __syncthreads();                              // prev QK/PV reads done before restage
#pragma unroll
    for (int c = 0; c < 4; c++) {                 // K tile 64x256B, swizzled
      int row = wave * 16 + c * 4 + krow;
      int g = (kslot & 8) | ((kslot ^ row) & 7);
      async16(Kbase + (size_t)(kt * 64 + row) * 128 + g * 8, sKc + (wave * 16 + c * 4) * 128);
    }
#pragma unroll
    for (int c = 0; c < 2; c++) {                 // V^T tile 64x128B, swizzled
      int row = wave * 16 + c * 8 + vrow;
      int g = vslot ^ (row & 7);
      async16(Vbase + (size_t)row * Sn + kt * 64 + g * 8, sVt + (wave * 16 + c * 8) * 64);
    }
    float mvalL[4];
#pragma unroll
    for (int jk = 0; jk < 4; jk++)
      mvalL[jk] = mbase[kt * 64 + jk * 16 + col15] * LOG2E;
    __syncthreads();

    // ---- S(log2-domain) = Qcat_scaled Kcat^T ----
    floatx4 sacc[2][4];
#pragma unroll
    for (int jk = 0; jk < 4; jk++) {
      sacc[0][jk] = (floatx4){0.f, 0.f, 0.f, 0.f};
      sacc[1][jk] = (floatx4){0.f, 0.f, 0.f, 0.f};
#pragma unroll
      for (int kk = 0; kk < 4; kk++) {
        int slot_ = (((kk * 4 + quad) & 8) | (((kk * 4 + quad) ^ col15) & 7)) * 8;
        short8 bk_ = *(const short8*)(sKc + (jk * 16 + col15) * 128 + slot_);
        sacc[0][jk] = __builtin_amdgcn_mfma_f32_16x16x32_bf16(aq[0][kk], bk_, sacc[0][jk], 0, 0, 0);
        sacc[1][jk] = __builtin_amdgcn_mfma_f32_16x16x32_bf16(aq[1][kk], bk_, sacc[1][jk], 0, 0, 0);
      }
    }

    // ---- no-max softmax: p = exp2(s + mask*log2e), bf16-trunc (l-consistent) ----
#pragma unroll
    for (int i = 0; i < 2; i++) {
      int rowb = wave * 32 + i * 16 + quad * 4;
#pragma unroll
      for (int jk = 0; jk < 4; jk++) {
        int colb = jk * 16 + col15;
#pragma unroll
        for (int r = 0; r < 4; r++) {
          float p = __builtin_amdgcn_exp2f(sacc[i][jk][r] + mvalL[jk]);
          unsigned pu = __float_as_uint(p) & 0xFFFF0000u;
          lsum[i][r] += __uint_as_float(pu);
          sS[(rowb + r) * LDV + colb] = (unsigned short)(pu >> 16);
        }
      }
    }
    // no barrier: sS rows are wave-private; intra-wave LDS RAW is ordered

    // ---- O += P V ----
#pragma unroll
    for (int kk = 0; kk < 2; kk++) {
      short8 ap0 = *(const short8*)(sS + (wave * 32 + col15) * LDV + kk * 32 + quad * 8);
      short8 ap1 = *(const short8*)(sS + (wave * 32 + 16 + col15) * LDV + kk * 32 + quad * 8);
      const int vslot_r = ((kk * 4 + quad) ^ (col15 & 7)) * 8;
#pragma unroll
      for (int j = 0; j < 4; j++) {
        short8 bv_ = *(const short8*)(sVt + (j * 16 + col15) * 64 + vslot_r);
        O[0][j] = __builtin_amdgcn_mfma_f32_16x16x32_bf16(ap0, bv_, O[0][j], 0, 0, 0);
        O[1][j] = __builtin_amdgcn_mfma_f32_16x16x32_bf16(ap1, bv_, O[1][j], 0, 0, 0);
      }
    }
  }

  // ---- epilogue: reduce l across the quad's 16 lanes, out = O / l ----
#pragma unroll
  for (int i = 0; i < 2; i++) {
#pragma unroll
    for (int r = 0; r < 4; r++) {
      float s_ = lsum[i][r];
      s_ += __shfl_xor(s_, 1);
      s_ += __shfl_xor(s_, 2);
      s_ += __shfl_xor(s_, 4);
      s_ += __shfl_xor(s_, 8);
      lsum[i][r] = 1.0f / s_;
    }
    int rowb = wave * 32 + i * 16 + quad * 4;
#pragma unroll
    for (int j = 0; j < 4; j++) {
      int dcol = h * 64 + j * 16 + col15;
      float* obase = out + ((size_t)b * Sn + q0 + rowb) * Dn + dcol;
      obase[0 * Dn] = O[i][j][0] * lsum[i][0];
      obase[1 * Dn] = O[i][j][1] * lsum[i][1];
      obase[2 * Dn] = O[i][j][2] * lsum[i][2];
      obase[3 * Dn] = O[i][j][3] * lsum[i][3];
    }
  }
}

extern "C" void kernel_launch(void* const* d_in, const int* in_sizes, int n_in,
                              void* d_out, int out_size, void* d_ws, size_t ws_size,
                              hipStream_t stream) {
  const float* hs   = (const float*)d_in[0];
  const float* lq   = (const float*)d_in[1];
  const float* lk   = (const float*)d_in[2];
  const float* mask = (const float*)d_in[3];
  const float* Wq   = (const float*)d_in[4];
  const float* bq   = (const float*)d_in[5];
  const float* Wk   = (const float*)d_in[6];
  const float* bk   = (const float*)d_in[7];
  const float* Wv   = (const float*)d_in[8];
  const float* bv   = (const float*)d_in[9];
  float* out = (float*)d_out;

  char* ws = (char*)d_ws;
  unsigned short* Xbf = (unsigned short*)ws;                         // [8192][768]
  unsigned short* Wbf = (unsigned short*)(ws + 12582912);            // [3][768][768]
  unsigned short* Qc  = (unsigned short*)(ws + 12582912 + 3538944);  // [48][2048][128]
  unsigned short* Kc  = Qc + (size_t)BHn * Sn * 128;
  unsigned short* Vt  = Kc + (size_t)BHn * Sn * 128;                 // [48][64][2048]

  cast_hs_kernel<<<6144, 256, 0, stream>>>(hs, Xbf, 1572864);
  cast_w_kernel<<<dim3(576, 3), 256, 0, stream>>>(Wq, Wk, Wv, Wbf);
  pack_layout_kernel<<<dim3(3072, 2), 256, 0, stream>>>(lq, lk, Qc, Kc);
  proj_kernel<<<dim3(6, 64, 3), 256, 0, stream>>>(Xbf, Wbf, bq, bk, bv, Qc, Kc, Vt);
  attn_kernel<<<768, 256, 0, stream>>>(Qc, Kc, Vt, mask, out);
}

// Round 7
// 273.082 us; speedup vs baseline: 1.1578x; 1.0114x over previous
//
#include <hip/hip_runtime.h>

// GMLLM dual-stream self-attention, MI355X/gfx950.  Round 10:
//  attn v3-swapped: KT=64 swapped-operand flash attn with ALL identified r5/r8
//  overheads removed and no exposed vmcnt drains:
//   - S^T = mfma(K,Q), O^T = mfma(V^T,P^T)  (r5/r6-verified layouts, 48 MFMA/tile = r0)
//   - lsum: per-lane truncated adds + 2 epilogue shfl_xor (l-MFMA deleted)
//   - P trunc-pack -> 8x b64 sS writes/tile (r6-verified), b128 reads (r5-verified)
//   - schedule: QK(t) -> barrier1 -> stage K(t+1) into SINGLE K buf + V(t+1) into
//     V dbuf -> softmax+PV(t) (~900cy covers load latency) -> barrier2 (drain ~done)
//   - LDS 48KB (sK 16 + sV dbuf 16 + sS 16) -> 3 blocks/CU, grid 768 zero-tail
//  proj/casts/pack identical to round 9 (passing).

typedef __attribute__((ext_vector_type(8))) short short8;   // 8 x bf16 (4 VGPRs) MFMA A/B frag
typedef __attribute__((ext_vector_type(4))) float floatx4;  // MFMA C/D frag

#define LOG2E 1.4426950408889634f
#define QSCL 0.18033688011112042f   /* 0.125 * log2(e) */

static constexpr int Sn = 2048, Dn = 768, Hn = 12, BHn = 48;

__device__ __forceinline__ unsigned short f2bf(float f) {
  unsigned u = __float_as_uint(f);
  u += 0x7FFFu + ((u >> 16) & 1u);          // RNE
  return (unsigned short)(u >> 16);
}

typedef const __attribute__((address_space(1))) unsigned int* gas_t;
typedef __attribute__((address_space(3))) unsigned int* las_t;
__device__ __forceinline__ void async16(const void* g, void* l) {
  // async 16B/lane global->LDS; LDS dest = wave-uniform base + lane*16
  __builtin_amdgcn_global_load_lds((gas_t)g, (las_t)l, 16, 0, 0);
}

// ---------------- cast hidden_states f32 -> bf16 (row-major [8192][768]) ----------------
__global__ void cast_hs_kernel(const float* __restrict__ in, unsigned short* __restrict__ out, int n4) {
  int i = blockIdx.x * 256 + threadIdx.x;
  if (i >= n4) return;
  float4 v = ((const float4*)in)[i];
  ushort4 o = make_ushort4(f2bf(v.x), f2bf(v.y), f2bf(v.z), f2bf(v.w));
  ((ushort4*)out)[i] = o;
}

// ---------------- cast Wq/Wk/Wv f32 -> bf16, stacked [3][768][768] ----------------
__global__ void cast_w_kernel(const float* __restrict__ w0, const float* __restrict__ w1,
                              const float* __restrict__ w2, unsigned short* __restrict__ out) {
  int i = blockIdx.x * 256 + threadIdx.x;
  const float* src = (blockIdx.y == 0) ? w0 : (blockIdx.y == 1) ? w1 : w2;
  float4 v = ((const float4*)src)[i];
  ushort4 o = make_ushort4(f2bf(v.x), f2bf(v.y), f2bf(v.z), f2bf(v.w));
  ((ushort4*)(out + (size_t)blockIdx.y * Dn * Dn))[i] = o;
}

// ---------------- pack layout_q (pre-scaled) / layout_k into upper half of Qc/Kc ----------------
__global__ void pack_layout_kernel(const float* __restrict__ lq, const float* __restrict__ lk,
                                   unsigned short* __restrict__ Qc, unsigned short* __restrict__ Kc) {
  int idx = blockIdx.x * 256 + threadIdx.x;           // 786432 threads
  const float* src = blockIdx.y ? lk : lq;
  unsigned short* dst = blockIdx.y ? Kc : Qc;
  const float sc = blockIdx.y ? 1.0f : QSCL;
  int d8 = idx & 7;
  int tt = idx >> 3;
  int h = tt % Hn;
  int bs = tt / Hn;
  int b = bs >> 11, s = bs & (Sn - 1);
  float4 v0 = ((const float4*)src)[idx * 2];
  float4 v1 = ((const float4*)src)[idx * 2 + 1];
  short8 o;
  o[0] = (short)f2bf(v0.x * sc); o[1] = (short)f2bf(v0.y * sc);
  o[2] = (short)f2bf(v0.z * sc); o[3] = (short)f2bf(v0.w * sc);
  o[4] = (short)f2bf(v1.x * sc); o[5] = (short)f2bf(v1.y * sc);
  o[6] = (short)f2bf(v1.z * sc); o[7] = (short)f2bf(v1.w * sc);
  size_t off = ((size_t)(b * Hn + h) * Sn + s) * 128 + 64 + d8 * 8;
  *(short8*)(dst + off) = o;
}

// ---------------- QKV projection (round-9 version, passing) ----------------
__global__ __launch_bounds__(256, 3)
void proj_kernel(const unsigned short* __restrict__ X,   // [8192][768] bf16
                 const unsigned short* __restrict__ Wb,  // [3][768][768] bf16
                 const float* __restrict__ bq, const float* __restrict__ bk, const float* __restrict__ bv,
                 unsigned short* __restrict__ Qc, unsigned short* __restrict__ Kc,
                 unsigned short* __restrict__ Vt) {
  __shared__ __align__(16) unsigned short sMem[16384];

  const int z = blockIdx.z;
  const unsigned short* W = Wb + (size_t)z * Dn * Dn;
  const float* bias = (z == 0) ? bq : (z == 1) ? bk : bv;

  const int t = threadIdx.x;
  const int lane = t & 63, wave = t >> 6;
  const int wm = wave >> 1, wn = wave & 1;
  const int quad = lane >> 4, col15 = lane & 15;
  const int m0 = blockIdx.y * 128, n0 = blockIdx.x * 128;

  const int srow = lane >> 2, schunk = lane & 3;   // staging: 16 rows/call, 4 chunks/row

  floatx4 acc[4][4];
#pragma unroll
  for (int i = 0; i < 4; i++)
#pragma unroll
    for (int j = 0; j < 4; j++) acc[i][j] = (floatx4){0.f, 0.f, 0.f, 0.f};

  auto stageAB = [&](int kt, int buf) {
    unsigned short* sA = sMem + buf * 4096;
    unsigned short* sB = sMem + 8192 + buf * 4096;
#pragma unroll
    for (int c = 0; c < 2; c++) {
      int row = wave * 32 + c * 16 + srow;
      async16(X + (size_t)(m0 + row) * Dn + kt * 32 + schunk * 8, sA + (wave * 32 + c * 16) * 32);
      async16(W + (size_t)(n0 + row) * Dn + kt * 32 + schunk * 8, sB + (wave * 32 + c * 16) * 32);
    }
  };

  stageAB(0, 0);
  __syncthreads();

  for (int kt = 0; kt < 24; kt++) {
    const int cur = kt & 1;
    if (kt + 1 < 24) stageAB(kt + 1, cur ^ 1);
    const unsigned short* sA = sMem + cur * 4096;
    const unsigned short* sB = sMem + 8192 + cur * 4096;
    short8 af[4], bf[4];
#pragma unroll
    for (int i = 0; i < 4; i++)
      af[i] = *(const short8*)(sA + (wm * 64 + i * 16 + col15) * 32 + quad * 8);
#pragma unroll
    for (int j = 0; j < 4; j++)
      bf[j] = *(const short8*)(sB + (wn * 64 + j * 16 + col15) * 32 + quad * 8);
#pragma unroll
    for (int i = 0; i < 4; i++)
#pragma unroll
      for (int j = 0; j < 4; j++)
        acc[i][j] = __builtin_amdgcn_mfma_f32_16x16x32_bf16(af[i], bf[j], acc[i][j], 0, 0, 0);
    __syncthreads();
  }

  const int b = m0 >> 11;
  const int s0g = m0 & (Sn - 1);
  const int h0 = n0 >> 6;

  if (z < 2) {
    const float scl = (z == 0) ? QSCL : 1.0f;
    unsigned short* dst0 = (z == 0) ? Qc : Kc;
#pragma unroll
    for (int j = 0; j < 4; j++) {
      int nl = wn * 64 + j * 16 + col15;
      float bias_n = bias[n0 + nl];
#pragma unroll
      for (int i = 0; i < 4; i++) {
        int mb = wm * 64 + i * 16 + quad * 4;
#pragma unroll
        for (int r = 0; r < 4; r++) {
          int m = mb + r;
          sMem[m * 128 + (nl ^ (((m >> 2) & 3) << 4))] = f2bf((acc[i][j][r] + bias_n) * scl);
        }
      }
    }
    __syncthreads();
#pragma unroll
    for (int cc = 0; cc < 8; cc++) {
      int idx = cc * 256 + t;
      int m = idx >> 4, piece = idx & 15;
      int h = h0 + (piece >> 3), d8 = piece & 7;
      short8 v = *(const short8*)(sMem + m * 128 + (piece ^ (((m >> 2) & 3) << 1)) * 8);
      *(short8*)(dst0 + ((size_t)(b * Hn + h) * Sn + s0g + m) * 128 + d8 * 8) = v;
    }
  } else {
#pragma unroll
    for (int j = 0; j < 4; j++) {
      int nl = wn * 64 + j * 16 + col15;
      float bias_n = bias[n0 + nl];
#pragma unroll
      for (int i = 0; i < 4; i++) {
        int mb = wm * 64 + i * 16 + quad * 4;
        ushort4 pk = make_ushort4(f2bf(acc[i][j][0] + bias_n), f2bf(acc[i][j][1] + bias_n),
                                  f2bf(acc[i][j][2] + bias_n), f2bf(acc[i][j][3] + bias_n));
        *(ushort4*)(sMem + nl * 128 + (mb ^ ((nl & 7) << 4))) = pk;
      }
    }
    __syncthreads();
#pragma unroll
    for (int cc = 0; cc < 8; cc++) {
      int idx = cc * 256 + t;
      int nl = idx >> 4, piece = idx & 15;
      int h = h0 + (nl >> 6), d = nl & 63;
      short8 v = *(const short8*)(sMem + nl * 128 + (piece ^ ((nl & 7) << 1)) * 8);
      *(short8*)(Vt + ((size_t)(b * Hn + h) * 64 + d) * Sn + s0g + piece * 8) = v;
    }
  }
}

// ---------------- flash attention v3: swapped operands, KT=64, no exposed drains ----------------
// S^T = mfma(K,Q): lane (quad,col15) reg r holds S[q = blk+col15][k = jm*16+quad*4+r], jm<4.
// P trunc-packed -> 8x b64 sS writes (phys col = k ^ ((col15&7)<<3)); PV reads b128 with the
// same involution.  O^T = mfma(V^T, P^T).  lsum = per-lane truncated adds, quad-reduced once.
// Schedule: QK(t) -> barrier1 -> stage K(t+1)(single buf) + V(t+1)(dbuf) -> softmax+PV(t)
// -> barrier2 (drains staging under ~900cy of compute).  LDS 48KB -> 3 blocks/CU.
__global__ __launch_bounds__(256, 3)
void attn_kernel(const unsigned short* __restrict__ Qc,  // [BH][S][128], pre-scaled by QSCL
                 const unsigned short* __restrict__ Kc,  // [BH][S][128]
                 const unsigned short* __restrict__ Vt,  // [BH][64][S]
                 const float* __restrict__ mask,         // [B][S]
                 float* __restrict__ out) {              // [B][S][768]
  __shared__ __align__(16) unsigned short sK[64 * 128];     // 16KB single buffer, swizzled
  __shared__ __align__(16) unsigned short sV2[2][64 * 64];  // 16KB dbuf, swizzled
  __shared__ __align__(16) unsigned short sS[128 * 64];     // 16KB P^T, wave-private rows

  const int t = threadIdx.x;
  const int lane = t & 63, wave = t >> 6;
  const int quad = lane >> 4, col15 = lane & 15;
  const int swz = (col15 & 7) << 3;                      // sS k swizzle (shorts): phys = k ^ swz

  // XCD-aware swizzle: all 16 q-blocks of one bh share id&7 (L2 K/V reuse)
  const int id = blockIdx.x;
  const int slot = id >> 3;
  const int bh = (id & 7) + 8 * (slot >> 4);
  const int q0 = (slot & 15) * 128;
  const int b = bh / Hn, h = bh % Hn;

  // Q fragments (B-operand: col=q=lane&15, k-rows quad*8)
  short8 aq[2][4];
  const unsigned short* Qbase = Qc + ((size_t)bh * Sn + q0) * 128;
#pragma unroll
  for (int i = 0; i < 2; i++)
#pragma unroll
    for (int kk = 0; kk < 4; kk++)
      aq[i][kk] = *(const short8*)(Qbase + (size_t)(wave * 32 + i * 16 + col15) * 128 + kk * 32 + quad * 8);

  floatx4 O[2][4];
  float lsum[2] = {0.f, 0.f};
#pragma unroll
  for (int i = 0; i < 2; i++)
#pragma unroll
    for (int j = 0; j < 4; j++) O[i][j] = (floatx4){0.f, 0.f, 0.f, 0.f};

  const unsigned short* Kbase = Kc + (size_t)bh * Sn * 128;
  const unsigned short* Vbase = Vt + (size_t)bh * 64 * Sn;
  const float* mbase = mask + (size_t)b * Sn;

  const int krow = lane >> 4, kslot = lane & 15;  // sK staging: 4 rows/call
  const int vrow = lane >> 3, vslot = lane & 7;   // sV staging: 8 rows/call

  auto stageK = [&](int tile) {
#pragma unroll
    for (int c = 0; c < 4; c++) {                 // K tile 64x256B, swizzled
      int row = wave * 16 + c * 4 + krow;
      int g = (kslot & 8) | ((kslot ^ row) & 7);
      async16(Kbase + (size_t)(tile * 64 + row) * 128 + g * 8, sK + (wave * 16 + c * 4) * 128);
    }
  };
  auto stageV = [&](int tile, int buf) {
    unsigned short* sVn = &sV2[buf][0];
#pragma unroll
    for (int c = 0; c < 2; c++) {                 // V^T tile 64x128B, swizzled
      int row = wave * 16 + c * 8 + vrow;
      int g = vslot ^ (row & 7);
      async16(Vbase + (size_t)row * Sn + tile * 64 + g * 8, sVn + (wave * 16 + c * 8) * 64);
    }
  };

  constexpr int NT = Sn / 64;                     // 32 tiles
  stageK(0);
  stageV(0, 0);
  float mcur = mbase[lane] * LOG2E;               // tile-0 mask dword
  __syncthreads();                                // drain prologue staging

  for (int kt = 0; kt < NT; kt++) {
    const int cur = kt & 1;
    const unsigned short* sVcur = &sV2[cur][0];

    // ---- S^T(log2-domain) = Kcat Qcat^T  (reads sK) ----
    floatx4 sacc[4][2];                           // [jm = k subtile][iq]
#pragma unroll
    for (int jm = 0; jm < 4; jm++) {
      sacc[jm][0] = (floatx4){0.f, 0.f, 0.f, 0.f};
      sacc[jm][1] = (floatx4){0.f, 0.f, 0.f, 0.f};
    }
    __builtin_amdgcn_s_setprio(1);
#pragma unroll
    for (int kk = 0; kk < 4; kk++) {
      const int slotK = (((kk * 4 + quad) & 8) | (((kk * 4 + quad) ^ col15) & 7)) * 8;
#pragma unroll
      for (int jm = 0; jm < 4; jm++) {
        short8 ak = *(const short8*)(sK + (jm * 16 + col15) * 128 + slotK);
        sacc[jm][0] = __builtin_amdgcn_mfma_f32_16x16x32_bf16(ak, aq[0][kk], sacc[jm][0], 0, 0, 0);
        sacc[jm][1] = __builtin_amdgcn_mfma_f32_16x16x32_bf16(ak, aq[1][kk], sacc[jm][1], 0, 0, 0);
      }
    }
    __builtin_amdgcn_s_setprio(0);

    const int tn = (kt + 1 < NT) ? kt + 1 : NT - 1;
    float mnew = mbase[tn * 64 + lane] * LOG2E;   // prefetch next tile's mask
    const bool nomask = __all(mcur == 0.0f);

    __syncthreads();                              // barrier1: all waves done reading sK
    if (kt + 1 < NT) {
      stageK(kt + 1);                             // rewrite single K buffer
      stageV(kt + 1, cur ^ 1);                    // fill other V buffer
    }

    // mask slow path: per-element additive value via lane shuffle (exact)
    float mvv[4][4];
    if (!nomask) {
#pragma unroll
      for (int jm = 0; jm < 4; jm++)
#pragma unroll
        for (int r = 0; r < 4; r++) mvv[jm][r] = __shfl(mcur, jm * 16 + quad * 4 + r);
    }

    // ---- softmax: p = exp2(s (+ mask)); trunc-pack -> b64 sS writes; lsum adds ----
#pragma unroll
    for (int iq = 0; iq < 2; iq++) {
      unsigned short* srow = sS + (wave * 32 + iq * 16 + col15) * 64;
      float lacc = 0.f;
#pragma unroll
      for (int jm = 0; jm < 4; jm++) {
        float p0 = sacc[jm][iq][0], p1 = sacc[jm][iq][1];
        float p2 = sacc[jm][iq][2], p3 = sacc[jm][iq][3];
        if (!nomask) { p0 += mvv[jm][0]; p1 += mvv[jm][1]; p2 += mvv[jm][2]; p3 += mvv[jm][3]; }
        unsigned u0 = __float_as_uint(__builtin_amdgcn_exp2f(p0)) & 0xFFFF0000u;
        unsigned u1 = __float_as_uint(__builtin_amdgcn_exp2f(p1)) & 0xFFFF0000u;
        unsigned u2 = __float_as_uint(__builtin_amdgcn_exp2f(p2)) & 0xFFFF0000u;
        unsigned u3 = __float_as_uint(__builtin_amdgcn_exp2f(p3)) & 0xFFFF0000u;
        lacc += (__uint_as_float(u0) + __uint_as_float(u1)) +
                (__uint_as_float(u2) + __uint_as_float(u3));
        uint2 w;
        w.x = (u0 >> 16) | u1;
        w.y = (u2 >> 16) | u3;
        *(uint2*)(srow + ((jm * 16 + quad * 4) ^ swz)) = w;
      }
      lsum[iq] += lacc;
    }
    // no barrier: sS rows are wave-private; intra-wave LDS RAW is ordered

    // ---- O^T += V^T P^T  (reads sS + sVcur) ----
    __builtin_amdgcn_s_setprio(1);
#pragma unroll
    for (int kk = 0; kk < 2; kk++) {
      short8 pb0 = *(const short8*)(sS + (wave * 32 + col15) * 64 + ((kk * 32 + quad * 8) ^ swz));
      short8 pb1 = *(const short8*)(sS + (wave * 32 + 16 + col15) * 64 + ((kk * 32 + quad * 8) ^ swz));
      const int slotV = ((kk * 4 + quad) ^ (col15 & 7)) * 8;
#pragma unroll
      for (int jd = 0; jd < 4; jd++) {
        short8 av = *(const short8*)(sVcur + (jd * 16 + col15) * 64 + slotV);
        O[0][jd] = __builtin_amdgcn_mfma_f32_16x16x32_bf16(av, pb0, O[0][jd], 0, 0, 0);
        O[1][jd] = __builtin_amdgcn_mfma_f32_16x16x32_bf16(av, pb1, O[1][jd], 0, 0, 0);
      }
    }
    __builtin_amdgcn_s_setprio(0);

    __syncthreads();  // barrier2: drains K(t+1)/V(t+1) staging (issued ~900cy ago);
                      // all waves' PV reads of sVcur done before t+2 overwrites it
    mcur = mnew;
  }

  // ---- epilogue: l[q] = quad-reduced lsum; O^T cols divided, float4 stores ----
#pragma unroll
  for (int iq = 0; iq < 2; iq++) {
    float s_ = lsum[iq];
    s_ += __shfl_xor(s_, 16);
    s_ += __shfl_xor(s_, 32);
    float inv = 1.0f / s_;
    int qrow = q0 + wave * 32 + iq * 16 + col15;
    float* obase = out + ((size_t)b * Sn + qrow) * Dn + h * 64 + quad * 4;
#pragma unroll
    for (int jd = 0; jd < 4; jd++) {
      float4 o4 = make_float4(O[iq][jd][0] * inv, O[iq][jd][1] * inv,
                              O[iq][jd][2] * inv, O[iq][jd][3] * inv);
      *(float4*)(obase + jd * 16) = o4;
    }
  }
}

extern "C" void kernel_launch(void* const* d_in, const int* in_sizes, int n_in,
                              void* d_out, int out_size, void* d_ws, size_t ws_size,
                              hipStream_t stream) {
  const float* hs   = (const float*)d_in[0];
  const float* lq   = (const float*)d_in[1];
  const float* lk   = (const float*)d_in[2];
  const float* mask = (const float*)d_in[3];
  const float* Wq   = (const float*)d_in[4];
  const float* bq   = (const float*)d_in[5];
  const float* Wk   = (const float*)d_in[6];
  const float* bk   = (const float*)d_in[7];
  const float* Wv   = (const float*)d_in[8];
  const float* bv   = (const float*)d_in[9];
  float* out = (float*)d_out;

  char* ws = (char*)d_ws;
  unsigned short* Xbf = (unsigned short*)ws;                         // [8192][768]
  unsigned short* Wbf = (unsigned short*)(ws + 12582912);            // [3][768][768]
  unsigned short* Qc  = (unsigned short*)(ws + 12582912 + 3538944);  // [48][2048][128]
  unsigned short* Kc  = Qc + (size_t)BHn * Sn * 128;
  unsigned short* Vt  = Kc + (size_t)BHn * Sn * 128;                 // [48][64][2048]

  cast_hs_kernel<<<6144, 256, 0, stream>>>(hs, Xbf, 1572864);
  cast_w_kernel<<<dim3(576, 3), 256, 0, stream>>>(Wq, Wk, Wv, Wbf);
  pack_layout_kernel<<<dim3(3072, 2), 256, 0, stream>>>(lq, lk, Qc, Kc);
  proj_kernel<<<dim3(6, 64, 3), 256, 0, stream>>>(Xbf, Wbf, bq, bk, bv, Qc, Kc, Vt);
  attn_kernel<<<768, 256, 0, stream>>>(Qc, Kc, Vt, mask, out);
}